// Round 8
// baseline (898.117 us; speedup 1.0000x reference)
//
#include <hip/hip_runtime.h>
#include <hip/hip_bf16.h>

#define D 128
constexpr int V_N    = 100000;
constexpr int E_N    = 600000;
constexpr int HALF_E = E_N / 2;
constexpr int NREL2  = 100;
constexpr int NBUCK  = 2 * NREL2;   // 200 edge buckets; M index 200 = self-loop
constexpr float BN_EPS_F = 1e-5f;

constexpr int CHUNK  = 4096;
constexpr int NCHUNK = (E_N + CHUNK - 1) / CHUNK;   // 147

typedef short bf16x8  __attribute__((ext_vector_type(8)));   // 8 bf16 (4 VGPRs)
typedef float f32x16  __attribute__((ext_vector_type(16)));  // MFMA 32x32 acc
typedef float f32x4v  __attribute__((ext_vector_type(4)));
typedef unsigned int uint32;

// ================= pk-bf16 (R7 fallback) workspace layout =================
constexpr size_t MT_BYTES  = 201ull * D * D * 2;             // 6,586,368
constexpr size_t P_SS_OFF  = MT_BYTES;
constexpr size_t P_SD_OFF  = P_SS_OFF + (size_t)E_N * 4;
constexpr size_t P_SN_OFF  = P_SD_OFF + (size_t)E_N * 4;
constexpr size_t P_AGG_OFF = P_SN_OFF + (size_t)E_N * 4;     // bf16[V][D]
constexpr size_t AGG_BYTES = (size_t)V_N * D * 2;            // 25.6 MB
constexpr size_t P_HIST_OFF = P_AGG_OFF;                     // overlay (dead after sort)
constexpr size_t P_COFF_OFF = P_HIST_OFF + (size_t)NBUCK * NCHUNK * 4;
constexpr size_t P_CS_OFF  = P_AGG_OFF + AGG_BYTES;
constexpr size_t P_CQ_OFF  = P_CS_OFF + 512;
constexpr size_t P_CNT_OFF = P_CQ_OFF + 512;
constexpr size_t P_ST_OFF  = P_CNT_OFF + 1024;
constexpr size_t WS_NEED_PK = P_ST_OFF + 1024;               // ~39.4 MB

// ================= V3 (two-phase, no scatter atomics) layout =================
constexpr size_t V3_MT    = 0;                                   // 6,586,368
constexpr size_t V3_SS    = MT_BYTES;                            // ssrc
constexpr size_t V3_SD    = V3_SS + (size_t)E_N * 4;             // sdst
constexpr size_t V3_SN    = V3_SD + (size_t)E_N * 4;             // snorm
constexpr size_t V3_XBF   = V3_SN + (size_t)E_N * 4;             // bf16[V][D]
constexpr size_t V3_AGG   = V3_XBF + (size_t)V_N * D * 2;        // bf16[V][D]
constexpr size_t V3_DEG   = V3_AGG + AGG_BYTES;                  // int[V]
constexpr size_t V3_RP    = V3_DEG + (size_t)V_N * 4;            // rowptr int[V+1] (pad)
constexpr size_t V3_CUR   = V3_RP + (size_t)(V_N + 16) * 4;      // cursor int[V]
constexpr size_t V3_EIDX  = V3_CUR + (size_t)V_N * 4;            // int[E]
constexpr size_t V3_HIST  = V3_EIDX + (size_t)E_N * 4;
constexpr size_t V3_COFF  = V3_HIST + (size_t)NBUCK * NCHUNK * 4;
constexpr size_t V3_CNT   = V3_COFF + (size_t)NBUCK * NCHUNK * 4;
constexpr size_t V3_START = V3_CNT + 1024;
constexpr size_t V3_BSUM  = V3_START + 1024;
constexpr size_t V3_CS    = V3_BSUM + 1024;                      // colsum 512
constexpr size_t V3_CQ    = V3_CS + 512;                         // colsq 512
constexpr size_t V3_MSG   = (V3_CQ + 512 + 255) & ~(size_t)255;  // msg (variable)
// zeroed region: V3_AGG..V3_DEG+V*4 contiguous (agg+deg), plus colsum/colsq

constexpr int SCAN_ELEMS = 1024;
constexpr int NSCANB = (V_N + SCAN_ELEMS - 1) / SCAN_ELEMS;      // 98

__device__ inline unsigned short f2bf(float f) {
    __hip_bfloat16 h = __float2bfloat16(f);               // RNE
    return __builtin_bit_cast(unsigned short, h);
}
__device__ inline float bf2f(unsigned int u) {
    return __uint_as_float(u << 16);
}

__device__ inline int bucket_of(int e, const int* __restrict__ etype) {
    return etype[e] + (e < HALF_E ? 0 : NREL2);
}

// ---------------- bucket sort phase 1: per-chunk histogram ----------------
__global__ __launch_bounds__(256) void k_hist_chunk(const int* __restrict__ etype,
                                                    int* __restrict__ hist) {
    __shared__ int h[NBUCK];
    for (int i = threadIdx.x; i < NBUCK; i += 256) h[i] = 0;
    __syncthreads();
    int c = blockIdx.x;
    int e0 = c * CHUNK;
#pragma unroll
    for (int r = 0; r < CHUNK / 256; r++) {
        int e = e0 + r * 256 + threadIdx.x;
        if (e < E_N) atomicAdd(&h[bucket_of(e, etype)], 1);
    }
    __syncthreads();
    for (int b = threadIdx.x; b < NBUCK; b += 256) hist[b * NCHUNK + c] = h[b];
}

// ---------------- bucket sort phase 2: per-bucket scan over chunks ----------------
__global__ void k_scan_bucket(const int* __restrict__ hist, int* __restrict__ chunkoff,
                              int* __restrict__ counts) {
    int b = blockIdx.x, lane = threadIdx.x;   // 64 lanes
    int acc = 0;
    for (int base = 0; base < NCHUNK; base += 64) {
        int c = base + lane;
        int v = (c < NCHUNK) ? hist[b * NCHUNK + c] : 0;
        int s = v;
#pragma unroll
        for (int off = 1; off < 64; off <<= 1) {
            int t = __shfl(s, lane - off, 64);
            if (lane >= off) s += t;
        }
        if (c < NCHUNK) chunkoff[b * NCHUNK + c] = acc + (s - v);
        acc += __shfl(s, 63, 64);
    }
    if (lane == 0) counts[b] = acc;
}

// ---------------- bucket sort phase 3: bucket starts ----------------
__global__ void k_scan(const int* __restrict__ counts, int* __restrict__ starts) {
    __shared__ int s[256];
    int i = threadIdx.x;
    int v = (i < NBUCK) ? counts[i] : 0;
    s[i] = v;
    __syncthreads();
    for (int off = 1; off < 256; off <<= 1) {
        int t = (i >= off) ? s[i - off] : 0;
        __syncthreads();
        s[i] += t;
        __syncthreads();
    }
    if (i < NBUCK) starts[i] = s[i] - v;
    if (i == 255) starts[NBUCK] = s[255];
}

// ---------------- bucket sort phase 4: scatter with LDS ranks ----------------
__global__ __launch_bounds__(256) void k_scatter2(
    const int* __restrict__ src, const int* __restrict__ dst,
    const float* __restrict__ norm, const int* __restrict__ etype,
    const int* __restrict__ starts, const int* __restrict__ chunkoff,
    int* __restrict__ ssrc, int* __restrict__ sdst, float* __restrict__ snorm) {
    __shared__ int h[NBUCK];
    __shared__ int sbase[NBUCK];
    int c = blockIdx.x;
    for (int b = threadIdx.x; b < NBUCK; b += 256) {
        h[b] = 0;
        sbase[b] = starts[b] + chunkoff[b * NCHUNK + c];
    }
    __syncthreads();
    int e0 = c * CHUNK;
#pragma unroll
    for (int r = 0; r < CHUNK / 256; r++) {
        int e = e0 + r * 256 + threadIdx.x;
        if (e < E_N) {
            int b = bucket_of(e, etype);
            int rank = atomicAdd(&h[b], 1);
            int p = sbase[b] + rank;
            ssrc[p] = src[e]; sdst[p] = dst[e]; snorm[p] = norm[e];
        }
    }
}

// ---------------- x -> bf16 precompute ----------------
__global__ __launch_bounds__(256) void k_xbf(const float* __restrict__ x,
                                             ushort* __restrict__ xbf) {
    const int N8 = V_N * D / 8;   // 1.6M
    int i = blockIdx.x * 256 + threadIdx.x;
    if (i >= N8) return;
    f32x4v v0 = *(const f32x4v*)&x[(size_t)i * 8];
    f32x4v v1 = *(const f32x4v*)&x[(size_t)i * 8 + 4];
    union { ushort u[8]; uint4 q; } t;
    t.u[0] = f2bf(v0[0]); t.u[1] = f2bf(v0[1]); t.u[2] = f2bf(v0[2]); t.u[3] = f2bf(v0[3]);
    t.u[4] = f2bf(v1[0]); t.u[5] = f2bf(v1[1]); t.u[6] = f2bf(v1[2]); t.u[7] = f2bf(v1[3]);
    *(uint4*)&xbf[(size_t)i * 8] = t.q;
}

// ---------------- build transposed bf16 M matrices ----------------
__global__ void k_build_M(const float* __restrict__ rel, const float* __restrict__ in_w,
                          const float* __restrict__ out_w, const float* __restrict__ loop_rel,
                          const float* __restrict__ loop_w, ushort* __restrict__ MT) {
    extern __shared__ float smem[];
    float* sW = smem;            // 128*128
    float* sR = smem + D * D;    // 256
    int b = blockIdx.x;
    const float* r = (b < NREL2) ? rel + (size_t)b * D
                   : (b < NBUCK) ? rel + (size_t)(b - NREL2) * D : loop_rel;
    const float* W = (b < NREL2) ? in_w : (b < NBUCK) ? out_w : loop_w;
    for (int i = threadIdx.x; i < D * D; i += blockDim.x) sW[i] = W[i];
    for (int i = threadIdx.x; i < D; i += blockDim.x) { float v = r[i]; sR[i] = v; sR[i + D] = v; }
    __syncthreads();
    int o  = threadIdx.x & 127;
    int jg = threadIdx.x >> 7;
    ushort* MTb = MT + (size_t)b * (D * D);
    for (int pass = 0; pass < 4; pass++) {
        int jbase = jg * 64 + pass * 16;
        float acc[16];
#pragma unroll
        for (int t = 0; t < 16; t++) acc[t] = 0.f;
        for (int k = 0; k < D; k++) {
            float w = sW[k * D + o];
#pragma unroll
            for (int t = 0; t < 16; t++) acc[t] += sR[jbase + t + k] * w;
        }
#pragma unroll
        for (int t = 0; t < 16; t++) MTb[(size_t)o * D + jbase + t] = f2bf(acc[t]);
    }
}

// ---------------- output 1: rel @ w_rel ----------------
__global__ void k_relw(const float* __restrict__ rel, const float* __restrict__ w_rel,
                       float* __restrict__ out2) {
    int rr = blockIdx.x, o = threadIdx.x;
    float acc = 0.f;
    for (int k = 0; k < D; k++) acc += rel[rr * D + k] * w_rel[k * D + o];
    out2[rr * D + o] = acc;
}

// ---------------- dst CSR: degree histogram ----------------
__global__ __launch_bounds__(256) void k_deg(const int* __restrict__ sdst,
                                             int* __restrict__ deg) {
    int p = blockIdx.x * 256 + threadIdx.x;
    if (p < E_N) atomicAdd(&deg[sdst[p]], 1);
}

// ---------------- dst CSR: scan stage 1 (per-block) ----------------
__global__ __launch_bounds__(256) void k_scan1(const int* __restrict__ deg,
                                               int* __restrict__ rowptr,
                                               int* __restrict__ blocksum) {
    __shared__ int s[256];
    int blk = blockIdx.x, tid = threadIdx.x;
    int base = blk * SCAN_ELEMS + tid * 4;
    int v[4]; int tot = 0;
#pragma unroll
    for (int j = 0; j < 4; j++) { int i = base + j; v[j] = (i < V_N) ? deg[i] : 0; tot += v[j]; }
    s[tid] = tot;
    __syncthreads();
    for (int off = 1; off < 256; off <<= 1) {
        int t = (tid >= off) ? s[tid - off] : 0;
        __syncthreads();
        s[tid] += t;
        __syncthreads();
    }
    int run = s[tid] - tot;
#pragma unroll
    for (int j = 0; j < 4; j++) { int i = base + j; if (i < V_N) rowptr[i] = run; run += v[j]; }
    if (tid == 255) blocksum[blk] = s[255];
}

// ---------------- dst CSR: scan stage 2 (block sums, in place excl) ----------------
__global__ void k_scan2(int* __restrict__ blocksum) {
    __shared__ int s[128];
    int i = threadIdx.x;
    int v = (i < NSCANB) ? blocksum[i] : 0;
    s[i] = v;
    __syncthreads();
    for (int off = 1; off < 128; off <<= 1) {
        int t = (i >= off) ? s[i - off] : 0;
        __syncthreads();
        s[i] += t;
        __syncthreads();
    }
    if (i < NSCANB) blocksum[i] = s[i] - v;
}

// ---------------- dst CSR: scan stage 3 (add back, init cursor) ----------------
__global__ __launch_bounds__(256) void k_scan3(int* __restrict__ rowptr,
                                               const int* __restrict__ blocksum,
                                               int* __restrict__ cursor) {
    int i = blockIdx.x * 256 + threadIdx.x;
    if (i < V_N) {
        int r = rowptr[i] + blocksum[i >> 10];
        rowptr[i] = r; cursor[i] = r;
    }
    if (i == 0) rowptr[V_N] = E_N;
}

// ---------------- dst CSR: permutation scatter ----------------
__global__ __launch_bounds__(256) void k_perm(const int* __restrict__ sdst,
                                              int* __restrict__ cursor,
                                              int* __restrict__ eidx) {
    int p = blockIdx.x * 256 + threadIdx.x;
    if (p < E_N) {
        int slot = atomicAdd(&cursor[sdst[p]], 1);
        eidx[slot] = p;
    }
}

constexpr int BPB = 8;   // blocks per bucket -> 16 streams/bucket

// ---------------- phase 1: edge messages (MFMA) -> streaming msg store ----------------
// Tiles are GLOBALLY 32-aligned so [lo,hi) ranges (32-multiples) partition cleanly.
// msg32[(p-lo)*64 + j] = pk(cols 2j, 2j+1) of msg row p (x norm).
__global__ __launch_bounds__(256) void k_edge_st(
    const ushort* __restrict__ xbf, const ushort* __restrict__ MT,
    const int* __restrict__ starts, const int* __restrict__ ssrc,
    const float* __restrict__ snorm, uint32* __restrict__ msg32,
    int lo, int hi) {
    int wid  = threadIdx.x >> 6, lane = threadIdx.x & 63;
    int l31  = lane & 31, l5 = lane >> 5;
    int bucket = blockIdx.x / BPB;
    int sib    = (blockIdx.x % BPB) * 2 + (wid >> 1);   // 0..15
    int oh     = wid & 1;
    int bstart = starts[bucket], bend = starts[bucket + 1];
    if (bstart >= bend || bstart >= hi || bend <= lo) return;
    const ushort* MTb = MT + (size_t)bucket * (D * D);
    int c0 = oh * 64 + 2 * l31;
    bf16x8 B0[8], B1[8];
#pragma unroll
    for (int kc = 0; kc < 8; kc++) {
        B0[kc] = *(const bf16x8*)&MTb[(size_t)c0 * D + kc * 16 + l5 * 8];
        B1[kc] = *(const bf16x8*)&MTb[(size_t)(c0 + 1) * D + kc * 16 + l5 * 8];
    }
    int t_first = (bstart > lo ? bstart : lo) & ~31;
    if (t_first < lo) t_first = lo;                    // (lo is 32-aligned; safety)
    int t_end = bend < hi ? bend : hi;
    for (int t = t_first + sib * 32; t < t_end; t += BPB * 2 * 32) {
        int pa = t + l31;
        bool va = (pa >= bstart) && (pa < bend);
        int sr = ssrc[va ? pa : bstart];
        const ushort* xr = xbf + (size_t)sr * D + l5 * 8;
        bf16x8 A[8];
#pragma unroll
        for (int kc = 0; kc < 8; kc++) A[kc] = *(const bf16x8*)(xr + kc * 16);
        f32x16 C0, C1;
#pragma unroll
        for (int i = 0; i < 16; i++) { C0[i] = 0.f; C1[i] = 0.f; }
#pragma unroll
        for (int kc = 0; kc < 8; kc++) {
            C0 = __builtin_amdgcn_mfma_f32_32x32x16_bf16(A[kc], B0[kc], C0, 0, 0, 0);
            C1 = __builtin_amdgcn_mfma_f32_32x32x16_bf16(A[kc], B1[kc], C1, 0, 0, 0);
        }
#pragma unroll
        for (int r = 0; r < 16; r++) {
            int rw = (r & 3) + 8 * (r >> 2) + 4 * l5;
            int p = t + rw;
            if (p >= bstart && p < bend) {
                float nm = snorm[p];
                uint32 u = (uint32)f2bf(C0[r] * nm) | ((uint32)f2bf(C1[r] * nm) << 16);
                msg32[(size_t)(p - lo) * 64 + oh * 32 + l31] = u;
            }
        }
    }
}

// ---------------- phase 2: segment sum by dst (1 wave / node) ----------------
__global__ __launch_bounds__(256) void k_segsum(
    const uint32* __restrict__ msg32, const int* __restrict__ eidx,
    const int* __restrict__ rowptr, uint32* __restrict__ agg32,
    int lo, int hi) {
    int v = blockIdx.x * 4 + (threadIdx.x >> 6);
    if (v >= V_N) return;
    int lane = threadIdx.x & 63;
    int s = rowptr[v], e = rowptr[v + 1];
    float a0 = 0.f, a1 = 0.f; int cnt = 0;
    for (int i = s; i < e; i++) {
        int p = eidx[i];
        if (p >= lo && p < hi) {
            uint32 u = msg32[(size_t)(p - lo) * 64 + lane];
            a0 += bf2f(u & 0xffffu); a1 += bf2f(u >> 16); cnt++;
        }
    }
    if (cnt) {
        size_t idx = (size_t)v * 64 + lane;
        uint32 u = agg32[idx];
        a0 += bf2f(u & 0xffffu); a1 += bf2f(u >> 16);
        agg32[idx] = (uint32)f2bf(a0) | ((uint32)f2bf(a1) << 16);
    }
}

// ---------------- self-loop GEMM (MFMA), bf16 x + bf16 agg -> fp32 out ----------------
constexpr int LOOP_GRID = 1563;   // 3126 streams, 1 tile each (NT=3125)
__global__ __launch_bounds__(256) void k_loop_v3(
    const ushort* __restrict__ xbf, const ushort* __restrict__ MT,
    const float* __restrict__ bias, const ushort* __restrict__ agg,
    float* __restrict__ out, float* __restrict__ colsum, float* __restrict__ colsq) {
    int wid = threadIdx.x >> 6, lane = threadIdx.x & 63;
    int l31 = lane & 31, l5 = lane >> 5;
    int oh  = wid & 1;
    int strm = blockIdx.x * 2 + (wid >> 1);
    const int NSTR = LOOP_GRID * 2;
    const ushort* MTb = MT + (size_t)NBUCK * (D * D);   // Mloop at index 200
    int ocol0 = oh * 64 + l31, ocol1 = oh * 64 + 32 + l31;
    bf16x8 B0[8], B1[8];
#pragma unroll
    for (int kc = 0; kc < 8; kc++) {
        B0[kc] = *(const bf16x8*)&MTb[(size_t)ocol0 * D + kc * 16 + l5 * 8];
        B1[kc] = *(const bf16x8*)&MTb[(size_t)ocol1 * D + kc * 16 + l5 * 8];
    }
    float b0 = bias[ocol0], b1 = bias[ocol1];
    float ps0 = 0.f, pq0 = 0.f, ps1 = 0.f, pq1 = 0.f;
    const int NT = V_N / 32;   // 3125
    for (int tile = strm; tile < NT; tile += NSTR) {
        int tbase = tile * 32;
        const ushort* xr = xbf + (size_t)(tbase + l31) * D + l5 * 8;
        bf16x8 A[8];
#pragma unroll
        for (int kc = 0; kc < 8; kc++) A[kc] = *(const bf16x8*)(xr + kc * 16);
        f32x16 C0, C1;
#pragma unroll
        for (int i = 0; i < 16; i++) { C0[i] = 0.f; C1[i] = 0.f; }
#pragma unroll
        for (int kc = 0; kc < 8; kc++) {
            C0 = __builtin_amdgcn_mfma_f32_32x32x16_bf16(A[kc], B0[kc], C0, 0, 0, 0);
            C1 = __builtin_amdgcn_mfma_f32_32x32x16_bf16(A[kc], B1[kc], C1, 0, 0, 0);
        }
#pragma unroll
        for (int r = 0; r < 16; r++) {
            int rw = (r & 3) + 8 * (r >> 2) + 4 * l5;
            size_t i0 = (size_t)(tbase + rw) * D + ocol0;
            size_t i1 = (size_t)(tbase + rw) * D + ocol1;
            float h0 = (bf2f((uint32)agg[i0]) + C0[r]) * (1.f / 3.f) + b0;
            float h1 = (bf2f((uint32)agg[i1]) + C1[r]) * (1.f / 3.f) + b1;
            out[i0] = h0; out[i1] = h1;
            ps0 += h0; pq0 += h0 * h0;
            ps1 += h1; pq1 += h1 * h1;
        }
    }
    atomicAdd(&colsum[ocol0], ps0); atomicAdd(&colsq[ocol0], pq0);
    atomicAdd(&colsum[ocol1], ps1); atomicAdd(&colsq[ocol1], pq1);
}

// ---------------- pk-bf16 fallback kernels (R7-measured path) ----------------
__global__ __launch_bounds__(256) void k_edge_pk(
    const float* __restrict__ x, const ushort* __restrict__ MT,
    const int* __restrict__ starts, const int* __restrict__ ssrc,
    const int* __restrict__ sdst, const float* __restrict__ snorm,
    ushort* __restrict__ agg) {
    int wid  = threadIdx.x >> 6, lane = threadIdx.x & 63;
    int l31  = lane & 31, l5 = lane >> 5;
    int bucket = blockIdx.x / BPB;
    int sib    = (blockIdx.x % BPB) * 2 + (wid >> 1);
    int oh     = wid & 1;
    int bstart = starts[bucket], bend = starts[bucket + 1];
    const ushort* MTb = MT + (size_t)bucket * (D * D);
    int c0 = oh * 64 + 2 * l31;
    bf16x8 B0[8], B1[8];
#pragma unroll
    for (int kc = 0; kc < 8; kc++) {
        B0[kc] = *(const bf16x8*)&MTb[(size_t)c0 * D + kc * 16 + l5 * 8];
        B1[kc] = *(const bf16x8*)&MTb[(size_t)(c0 + 1) * D + kc * 16 + l5 * 8];
    }
    for (int tbase = bstart + sib * 32; tbase < bend; tbase += BPB * 2 * 32) {
        int nv = bend - tbase; if (nv > 32) nv = 32;
        int sr = ssrc[tbase + (l31 < nv ? l31 : 0)];
        const float* xr = x + (size_t)sr * D + l5 * 8;
        bf16x8 A[8];
#pragma unroll
        for (int kc = 0; kc < 8; kc++) {
            f32x4v v0 = *(const f32x4v*)(xr + kc * 16);
            f32x4v v1 = *(const f32x4v*)(xr + kc * 16 + 4);
            union { bf16x8 v; ushort u[8]; } t;
            t.u[0] = f2bf(v0[0]); t.u[1] = f2bf(v0[1]); t.u[2] = f2bf(v0[2]); t.u[3] = f2bf(v0[3]);
            t.u[4] = f2bf(v1[0]); t.u[5] = f2bf(v1[1]); t.u[6] = f2bf(v1[2]); t.u[7] = f2bf(v1[3]);
            A[kc] = t.v;
        }
        f32x16 C0, C1;
#pragma unroll
        for (int i = 0; i < 16; i++) { C0[i] = 0.f; C1[i] = 0.f; }
#pragma unroll
        for (int kc = 0; kc < 8; kc++) {
            C0 = __builtin_amdgcn_mfma_f32_32x32x16_bf16(A[kc], B0[kc], C0, 0, 0, 0);
            C1 = __builtin_amdgcn_mfma_f32_32x32x16_bf16(A[kc], B1[kc], C1, 0, 0, 0);
        }
#pragma unroll
        for (int r = 0; r < 16; r++) {
            int rw = (r & 3) + 8 * (r >> 2) + 4 * l5;
            if (rw < nv) {
                float nm = snorm[tbase + rw];
                int   dv = sdst[tbase + rw];
                union { ushort u[2]; unsigned int w; } p;
                p.u[0] = f2bf(C0[r] * nm);
                p.u[1] = f2bf(C1[r] * nm);
                ushort* ap = agg + (size_t)dv * D + c0;
                asm volatile("global_atomic_pk_add_bf16 %0, %1, off"
                             :: "v"(ap), "v"(p.w) : "memory");
            }
        }
    }
}

__global__ __launch_bounds__(256) void k_loop_pk(
    const float* __restrict__ x, const ushort* __restrict__ MT,
    const float* __restrict__ bias, const ushort* __restrict__ agg,
    float* __restrict__ out, float* __restrict__ colsum, float* __restrict__ colsq) {
    int wid = threadIdx.x >> 6, lane = threadIdx.x & 63;
    int l31 = lane & 31, l5 = lane >> 5;
    int oh  = wid & 1;
    int strm = blockIdx.x * 2 + (wid >> 1);
    const int NSTR = LOOP_GRID * 2;
    const ushort* MTb = MT + (size_t)NBUCK * (D * D);
    int ocol0 = oh * 64 + l31, ocol1 = oh * 64 + 32 + l31;
    bf16x8 B0[8], B1[8];
#pragma unroll
    for (int kc = 0; kc < 8; kc++) {
        B0[kc] = *(const bf16x8*)&MTb[(size_t)ocol0 * D + kc * 16 + l5 * 8];
        B1[kc] = *(const bf16x8*)&MTb[(size_t)ocol1 * D + kc * 16 + l5 * 8];
    }
    float b0 = bias[ocol0], b1 = bias[ocol1];
    float ps0 = 0.f, pq0 = 0.f, ps1 = 0.f, pq1 = 0.f;
    const int NT = V_N / 32;
    for (int tile = strm; tile < NT; tile += NSTR) {
        int tbase = tile * 32;
        const float* xr = x + (size_t)(tbase + l31) * D + l5 * 8;
        bf16x8 A[8];
#pragma unroll
        for (int kc = 0; kc < 8; kc++) {
            f32x4v v0 = *(const f32x4v*)(xr + kc * 16);
            f32x4v v1 = *(const f32x4v*)(xr + kc * 16 + 4);
            union { bf16x8 v; ushort u[8]; } t;
            t.u[0] = f2bf(v0[0]); t.u[1] = f2bf(v0[1]); t.u[2] = f2bf(v0[2]); t.u[3] = f2bf(v0[3]);
            t.u[4] = f2bf(v1[0]); t.u[5] = f2bf(v1[1]); t.u[6] = f2bf(v1[2]); t.u[7] = f2bf(v1[3]);
            A[kc] = t.v;
        }
        f32x16 C0, C1;
#pragma unroll
        for (int i = 0; i < 16; i++) { C0[i] = 0.f; C1[i] = 0.f; }
#pragma unroll
        for (int kc = 0; kc < 8; kc++) {
            C0 = __builtin_amdgcn_mfma_f32_32x32x16_bf16(A[kc], B0[kc], C0, 0, 0, 0);
            C1 = __builtin_amdgcn_mfma_f32_32x32x16_bf16(A[kc], B1[kc], C1, 0, 0, 0);
        }
#pragma unroll
        for (int r = 0; r < 16; r++) {
            int rw = (r & 3) + 8 * (r >> 2) + 4 * l5;
            size_t i0 = (size_t)(tbase + rw) * D + ocol0;
            size_t i1 = (size_t)(tbase + rw) * D + ocol1;
            float h0 = (bf2f((uint32)agg[i0]) + C0[r]) * (1.f / 3.f) + b0;
            float h1 = (bf2f((uint32)agg[i1]) + C1[r]) * (1.f / 3.f) + b1;
            out[i0] = h0; out[i1] = h1;
            ps0 += h0; pq0 += h0 * h0;
            ps1 += h1; pq1 += h1 * h1;
        }
    }
    atomicAdd(&colsum[ocol0], ps0); atomicAdd(&colsq[ocol0], pq0);
    atomicAdd(&colsum[ocol1], ps1); atomicAdd(&colsq[ocol1], pq1);
}

// ---------------- BatchNorm normalize in place ----------------
__global__ void k_bn(float* __restrict__ out, const float* __restrict__ colsum,
                     const float* __restrict__ colsq, const float* __restrict__ gamma,
                     const float* __restrict__ beta) {
    const size_t N4 = (size_t)V_N * D / 4;
    size_t stride = (size_t)gridDim.x * blockDim.x;
    for (size_t q = (size_t)blockIdx.x * blockDim.x + threadIdx.x; q < N4; q += stride) {
        int c4 = (int)(q & 31);
        float4 s  = *(const float4*)&colsum[c4 * 4];
        float4 sq = *(const float4*)&colsq[c4 * 4];
        float4 g  = *(const float4*)&gamma[c4 * 4];
        float4 be = *(const float4*)&beta[c4 * 4];
        float4 h  = *(float4*)&out[q * 4];
        const float inv = 1.f / (float)V_N;
        float m0 = s.x * inv, m1 = s.y * inv, m2 = s.z * inv, m3 = s.w * inv;
        float r0 = rsqrtf(sq.x * inv - m0 * m0 + BN_EPS_F);
        float r1 = rsqrtf(sq.y * inv - m1 * m1 + BN_EPS_F);
        float r2 = rsqrtf(sq.z * inv - m2 * m2 + BN_EPS_F);
        float r3 = rsqrtf(sq.w * inv - m3 * m3 + BN_EPS_F);
        h.x = (h.x - m0) * r0 * g.x + be.x;
        h.y = (h.y - m1) * r1 * g.y + be.y;
        h.z = (h.z - m2) * r2 * g.z + be.z;
        h.w = (h.w - m3) * r3 * g.w + be.w;
        *(float4*)&out[q * 4] = h;
    }
}

extern "C" void kernel_launch(void* const* d_in, const int* in_sizes, int n_in,
                              void* d_out, int out_size, void* d_ws, size_t ws_size,
                              hipStream_t stream) {
    const float* x        = (const float*)d_in[0];
    const float* rel      = (const float*)d_in[1];
    const float* enorm    = (const float*)d_in[2];
    const float* in_w     = (const float*)d_in[3];
    const float* out_w    = (const float*)d_in[4];
    const float* loop_w   = (const float*)d_in[5];
    const float* w_rel    = (const float*)d_in[6];
    const float* loop_rel = (const float*)d_in[7];
    const float* bias     = (const float*)d_in[8];
    const float* gamma    = (const float*)d_in[9];
    const float* beta     = (const float*)d_in[10];
    const int*   esrc     = (const int*)d_in[11];
    const int*   edst     = (const int*)d_in[12];
    const int*   etype    = (const int*)d_in[13];
    float* out = (float*)d_out;
    char*  ws  = (char*)d_ws;

    const int gM = 201, smem = (D * D + 256) * sizeof(float);
    const int gE = (E_N + 255) / 256;

    // dynamic split sizing for the msg buffer
    size_t msg_cap = ws_size > V3_MSG ? ws_size - V3_MSG : 0;
    long cap_rows = (long)(msg_cap / 256) & ~31L;
    bool use_v3 = cap_rows >= 75008;   // S <= 8

    if (use_v3) {
        ushort* MT     = (ushort*)(ws + V3_MT);
        int*    ssrc   = (int*)(ws + V3_SS);
        int*    sdst   = (int*)(ws + V3_SD);
        float*  snorm  = (float*)(ws + V3_SN);
        ushort* xbf    = (ushort*)(ws + V3_XBF);
        ushort* aggbf  = (ushort*)(ws + V3_AGG);
        uint32* agg32  = (uint32*)(ws + V3_AGG);
        int*    deg    = (int*)(ws + V3_DEG);
        int*    rowptr = (int*)(ws + V3_RP);
        int*    cursor = (int*)(ws + V3_CUR);
        int*    eidx   = (int*)(ws + V3_EIDX);
        int*    hist   = (int*)(ws + V3_HIST);
        int*    coff   = (int*)(ws + V3_COFF);
        int*    counts = (int*)(ws + V3_CNT);
        int*    starts = (int*)(ws + V3_START);
        int*    bsum   = (int*)(ws + V3_BSUM);
        float*  colsum = (float*)(ws + V3_CS);
        float*  colsq  = (float*)(ws + V3_CQ);
        uint32* msg32  = (uint32*)(ws + V3_MSG);

        // zero agg+deg (contiguous) and BN partials
        hipMemsetAsync(ws + V3_AGG, 0, AGG_BYTES + (size_t)V_N * 4, stream);
        hipMemsetAsync(ws + V3_CS, 0, 1024, stream);

        // bucket counting sort
        k_hist_chunk<<<NCHUNK, 256, 0, stream>>>(etype, hist);
        k_scan_bucket<<<NBUCK, 64, 0, stream>>>(hist, coff, counts);
        k_scan<<<1, 256, 0, stream>>>(counts, starts);
        k_scatter2<<<NCHUNK, 256, 0, stream>>>(esrc, edst, enorm, etype, starts, coff,
                                               ssrc, sdst, snorm);
        // bf16 x
        k_xbf<<<(V_N * D / 8 + 255) / 256, 256, 0, stream>>>(x, xbf);
        // M matrices + rel output
        k_build_M<<<gM, 256, smem, stream>>>(rel, in_w, out_w, loop_rel, loop_w, MT);
        k_relw<<<NREL2, D, 0, stream>>>(rel, w_rel, out + (size_t)V_N * D);
        // dst CSR
        k_deg<<<gE, 256, 0, stream>>>(sdst, deg);
        k_scan1<<<NSCANB, 256, 0, stream>>>(deg, rowptr, bsum);
        k_scan2<<<1, 128, 0, stream>>>(bsum);
        k_scan3<<<(V_N + 255) / 256, 256, 0, stream>>>(rowptr, bsum, cursor);
        k_perm<<<gE, 256, 0, stream>>>(sdst, cursor, eidx);

        // two-phase edge aggregation over S splits
        int S = (int)((E_N + cap_rows - 1) / cap_rows);
        int range_len = (int)((((E_N + S - 1) / S) + 31) & ~31);
        for (int sIdx = 0; sIdx < S; sIdx++) {
            int lo = sIdx * range_len;
            int hi = lo + range_len;
            k_edge_st<<<NBUCK * BPB, 256, 0, stream>>>(xbf, MT, starts, ssrc, snorm,
                                                       msg32, lo, hi);
            k_segsum<<<(V_N + 3) / 4, 256, 0, stream>>>(msg32, eidx, rowptr, agg32, lo, hi);
        }

        k_loop_v3<<<LOOP_GRID, 256, 0, stream>>>(xbf, MT, bias, aggbf, out, colsum, colsq);
        k_bn<<<2048, 256, 0, stream>>>(out, colsum, colsq, gamma, beta);
    } else {
        // ---------- pk-bf16 fallback (R7-measured) ----------
        ushort* MT     = (ushort*)(ws + 0);
        int*    ssrc   = (int*)(ws + P_SS_OFF);
        int*    sdst   = (int*)(ws + P_SD_OFF);
        float*  snorm  = (float*)(ws + P_SN_OFF);
        ushort* aggbf  = (ushort*)(ws + P_AGG_OFF);
        int*    hist   = (int*)(ws + P_HIST_OFF);
        int*    coff   = (int*)(ws + P_COFF_OFF);
        float*  colsum = (float*)(ws + P_CS_OFF);
        float*  colsq  = (float*)(ws + P_CQ_OFF);
        int*    counts = (int*)(ws + P_CNT_OFF);
        int*    starts = (int*)(ws + P_ST_OFF);

        hipMemsetAsync(ws + P_CS_OFF, 0, 1024, stream);
        k_hist_chunk<<<NCHUNK, 256, 0, stream>>>(etype, hist);
        k_scan_bucket<<<NBUCK, 64, 0, stream>>>(hist, coff, counts);
        k_scan<<<1, 256, 0, stream>>>(counts, starts);
        k_scatter2<<<NCHUNK, 256, 0, stream>>>(esrc, edst, enorm, etype, starts, coff,
                                               ssrc, sdst, snorm);
        hipMemsetAsync(ws + P_AGG_OFF, 0, AGG_BYTES, stream);
        k_build_M<<<gM, 256, smem, stream>>>(rel, in_w, out_w, loop_rel, loop_w, MT);
        k_relw<<<NREL2, D, 0, stream>>>(rel, w_rel, out + (size_t)V_N * D);
        k_edge_pk<<<NBUCK * BPB, 256, 0, stream>>>(x, MT, starts, ssrc, sdst, snorm, aggbf);
        k_loop_pk<<<LOOP_GRID, 256, 0, stream>>>(x, MT, bias, aggbf, out, colsum, colsq);
        k_bn<<<2048, 256, 0, stream>>>(out, colsum, colsq, gamma, beta);
    }
}

// Round 9
// 458.639 us; speedup vs baseline: 1.9582x; 1.9582x over previous
//
#include <hip/hip_runtime.h>
#include <hip/hip_bf16.h>

#define D 128
constexpr int V_N    = 100000;
constexpr int E_N    = 600000;
constexpr int HALF_E = E_N / 2;
constexpr int NREL2  = 100;
constexpr int NBUCK  = 2 * NREL2;   // 200 edge buckets; M index 200 = self-loop
constexpr float BN_EPS_F = 1e-5f;

constexpr int CHUNK  = 4096;
constexpr int NCHUNK = (E_N + CHUNK - 1) / CHUNK;   // 147

typedef short bf16x8  __attribute__((ext_vector_type(8)));   // 8 bf16 (4 VGPRs)
typedef float f32x16  __attribute__((ext_vector_type(16)));  // MFMA 32x32 acc
typedef float f32x4v  __attribute__((ext_vector_type(4)));
typedef unsigned int uint32;

// ================= pk-bf16 workspace layout (R7-measured base) =================
constexpr size_t MT_BYTES  = 201ull * D * D * 2;             // 6,586,368
constexpr size_t P_SS_OFF  = MT_BYTES;
constexpr size_t P_SD_OFF  = P_SS_OFF + (size_t)E_N * 4;
constexpr size_t P_SN_OFF  = P_SD_OFF + (size_t)E_N * 4;
constexpr size_t P_AGG_OFF = P_SN_OFF + (size_t)E_N * 4;     // bf16[V][D]
constexpr size_t AGG_BYTES = (size_t)V_N * D * 2;            // 25.6 MB
constexpr size_t P_HIST_OFF = P_AGG_OFF;                     // overlay (dead after sort)
constexpr size_t P_COFF_OFF = P_HIST_OFF + (size_t)NBUCK * NCHUNK * 4;
constexpr size_t P_CS_OFF  = P_AGG_OFF + AGG_BYTES;          // colsum 512B
constexpr size_t P_CQ_OFF  = P_CS_OFF + 512;                 // colsq 512B
constexpr size_t P_CNT_OFF = P_CQ_OFF + 512;
constexpr size_t P_ST_OFF  = P_CNT_OFF + 1024;
constexpr size_t WS_NEED_PK = P_ST_OFF + 1024;               // ~39.4 MB

// ================= R9 additions: bf16 x + BN partials =================
constexpr int LOOP_GRID2 = 782;                              // 1564 streams, 2 tiles each
constexpr size_t P2_XBF  = (WS_NEED_PK + 255) & ~(size_t)255;   // bf16[V][D]
constexpr size_t P2_PSUM = P2_XBF + AGG_BYTES;               // f32[128][LOOP_GRID2]
constexpr size_t P2_PSQ  = P2_PSUM + 128ull * LOOP_GRID2 * 4;
constexpr size_t WS_NEED2 = P2_PSQ + 128ull * LOOP_GRID2 * 4;   // ~66 MB (ws >= 88 MB proven R8)

__device__ inline unsigned short f2bf(float f) {
    __hip_bfloat16 h = __float2bfloat16(f);               // RNE
    return __builtin_bit_cast(unsigned short, h);
}
__device__ inline float bf2f(unsigned int u) {
    return __uint_as_float(u << 16);
}

__device__ inline int bucket_of(int e, const int* __restrict__ etype) {
    return etype[e] + (e < HALF_E ? 0 : NREL2);
}

// ---------------- sort phase 1: per-chunk histogram (LDS only) ----------------
__global__ __launch_bounds__(256) void k_hist_chunk(const int* __restrict__ etype,
                                                    int* __restrict__ hist) {
    __shared__ int h[NBUCK];
    for (int i = threadIdx.x; i < NBUCK; i += 256) h[i] = 0;
    __syncthreads();
    int c = blockIdx.x;
    int e0 = c * CHUNK;
#pragma unroll
    for (int r = 0; r < CHUNK / 256; r++) {
        int e = e0 + r * 256 + threadIdx.x;
        if (e < E_N) atomicAdd(&h[bucket_of(e, etype)], 1);
    }
    __syncthreads();
    for (int b = threadIdx.x; b < NBUCK; b += 256) hist[b * NCHUNK + c] = h[b];
}

// ---------------- sort phase 2: per-bucket scan over chunks ----------------
__global__ void k_scan_bucket(const int* __restrict__ hist, int* __restrict__ chunkoff,
                              int* __restrict__ counts) {
    int b = blockIdx.x, lane = threadIdx.x;   // 64 lanes
    int acc = 0;
    for (int base = 0; base < NCHUNK; base += 64) {
        int c = base + lane;
        int v = (c < NCHUNK) ? hist[b * NCHUNK + c] : 0;
        int s = v;
#pragma unroll
        for (int off = 1; off < 64; off <<= 1) {
            int t = __shfl(s, lane - off, 64);
            if (lane >= off) s += t;
        }
        if (c < NCHUNK) chunkoff[b * NCHUNK + c] = acc + (s - v);
        acc += __shfl(s, 63, 64);
    }
    if (lane == 0) counts[b] = acc;
}

// ---------------- sort phase 3: bucket starts ----------------
__global__ void k_scan(const int* __restrict__ counts, int* __restrict__ starts) {
    __shared__ int s[256];
    int i = threadIdx.x;
    int v = (i < NBUCK) ? counts[i] : 0;
    s[i] = v;
    __syncthreads();
    for (int off = 1; off < 256; off <<= 1) {
        int t = (i >= off) ? s[i - off] : 0;
        __syncthreads();
        s[i] += t;
        __syncthreads();
    }
    if (i < NBUCK) starts[i] = s[i] - v;
    if (i == 255) starts[NBUCK] = s[255];
}

// ---------------- sort phase 4: scatter with LDS ranks ----------------
__global__ __launch_bounds__(256) void k_scatter2(
    const int* __restrict__ src, const int* __restrict__ dst,
    const float* __restrict__ norm, const int* __restrict__ etype,
    const int* __restrict__ starts, const int* __restrict__ chunkoff,
    int* __restrict__ ssrc, int* __restrict__ sdst, float* __restrict__ snorm) {
    __shared__ int h[NBUCK];
    __shared__ int sbase[NBUCK];
    int c = blockIdx.x;
    for (int b = threadIdx.x; b < NBUCK; b += 256) {
        h[b] = 0;
        sbase[b] = starts[b] + chunkoff[b * NCHUNK + c];
    }
    __syncthreads();
    int e0 = c * CHUNK;
#pragma unroll
    for (int r = 0; r < CHUNK / 256; r++) {
        int e = e0 + r * 256 + threadIdx.x;
        if (e < E_N) {
            int b = bucket_of(e, etype);
            int rank = atomicAdd(&h[b], 1);
            int p = sbase[b] + rank;
            ssrc[p] = src[e]; sdst[p] = dst[e]; snorm[p] = norm[e];
        }
    }
}

// ---------------- x -> bf16 precompute ----------------
__global__ __launch_bounds__(256) void k_xbf(const float* __restrict__ x,
                                             ushort* __restrict__ xbf) {
    const int N8 = V_N * D / 8;   // 1.6M
    int i = blockIdx.x * 256 + threadIdx.x;
    if (i >= N8) return;
    f32x4v v0 = *(const f32x4v*)&x[(size_t)i * 8];
    f32x4v v1 = *(const f32x4v*)&x[(size_t)i * 8 + 4];
    union { ushort u[8]; uint4 q; } t;
    t.u[0] = f2bf(v0[0]); t.u[1] = f2bf(v0[1]); t.u[2] = f2bf(v0[2]); t.u[3] = f2bf(v0[3]);
    t.u[4] = f2bf(v1[0]); t.u[5] = f2bf(v1[1]); t.u[6] = f2bf(v1[2]); t.u[7] = f2bf(v1[3]);
    *(uint4*)&xbf[(size_t)i * 8] = t.q;
}

// ---------------- build transposed bf16 M matrices ----------------
__global__ void k_build_M(const float* __restrict__ rel, const float* __restrict__ in_w,
                          const float* __restrict__ out_w, const float* __restrict__ loop_rel,
                          const float* __restrict__ loop_w, ushort* __restrict__ MT) {
    extern __shared__ float smem[];
    float* sW = smem;            // 128*128
    float* sR = smem + D * D;    // 256
    int b = blockIdx.x;
    const float* r = (b < NREL2) ? rel + (size_t)b * D
                   : (b < NBUCK) ? rel + (size_t)(b - NREL2) * D : loop_rel;
    const float* W = (b < NREL2) ? in_w : (b < NBUCK) ? out_w : loop_w;
    for (int i = threadIdx.x; i < D * D; i += blockDim.x) sW[i] = W[i];
    for (int i = threadIdx.x; i < D; i += blockDim.x) { float v = r[i]; sR[i] = v; sR[i + D] = v; }
    __syncthreads();
    int o  = threadIdx.x & 127;
    int jg = threadIdx.x >> 7;
    ushort* MTb = MT + (size_t)b * (D * D);
    for (int pass = 0; pass < 4; pass++) {
        int jbase = jg * 64 + pass * 16;
        float acc[16];
#pragma unroll
        for (int t = 0; t < 16; t++) acc[t] = 0.f;
        for (int k = 0; k < D; k++) {
            float w = sW[k * D + o];
#pragma unroll
            for (int t = 0; t < 16; t++) acc[t] += sR[jbase + t + k] * w;
        }
#pragma unroll
        for (int t = 0; t < 16; t++) MTb[(size_t)o * D + jbase + t] = f2bf(acc[t]);
    }
}

// ---------------- output 1: rel @ w_rel ----------------
__global__ void k_relw(const float* __restrict__ rel, const float* __restrict__ w_rel,
                       float* __restrict__ out2) {
    int rr = blockIdx.x, o = threadIdx.x;
    float acc = 0.f;
    for (int k = 0; k < D; k++) acc += rel[rr * D + k] * w_rel[k * D + o];
    out2[rr * D + o] = acc;
}

constexpr int BPB = 8;   // blocks per bucket -> 16 streams/bucket

// ---------------- edge messages (MFMA, bf16 x) + packed bf16 atomic scatter ----------------
__global__ __launch_bounds__(256) void k_edge_pkb(
    const ushort* __restrict__ xbf, const ushort* __restrict__ MT,
    const int* __restrict__ starts, const int* __restrict__ ssrc,
    const int* __restrict__ sdst, const float* __restrict__ snorm,
    ushort* __restrict__ agg) {
    int wid  = threadIdx.x >> 6, lane = threadIdx.x & 63;
    int l31  = lane & 31, l5 = lane >> 5;
    int bucket = blockIdx.x / BPB;
    int sib    = (blockIdx.x % BPB) * 2 + (wid >> 1);   // 0..15
    int oh     = wid & 1;
    int bstart = starts[bucket], bend = starts[bucket + 1];
    const ushort* MTb = MT + (size_t)bucket * (D * D);
    int c0 = oh * 64 + 2 * l31;          // even col; odd partner is c0+1
    bf16x8 B0[8], B1[8];
#pragma unroll
    for (int kc = 0; kc < 8; kc++) {
        B0[kc] = *(const bf16x8*)&MTb[(size_t)c0 * D + kc * 16 + l5 * 8];
        B1[kc] = *(const bf16x8*)&MTb[(size_t)(c0 + 1) * D + kc * 16 + l5 * 8];
    }
    for (int tbase = bstart + sib * 32; tbase < bend; tbase += BPB * 2 * 32) {
        int nv = bend - tbase; if (nv > 32) nv = 32;
        int sr = ssrc[tbase + (l31 < nv ? l31 : 0)];
        const ushort* xr = xbf + (size_t)sr * D + l5 * 8;
        bf16x8 A[8];
#pragma unroll
        for (int kc = 0; kc < 8; kc++) A[kc] = *(const bf16x8*)(xr + kc * 16);
        f32x16 C0, C1;
#pragma unroll
        for (int i = 0; i < 16; i++) { C0[i] = 0.f; C1[i] = 0.f; }
#pragma unroll
        for (int kc = 0; kc < 8; kc++) {
            C0 = __builtin_amdgcn_mfma_f32_32x32x16_bf16(A[kc], B0[kc], C0, 0, 0, 0);
            C1 = __builtin_amdgcn_mfma_f32_32x32x16_bf16(A[kc], B1[kc], C1, 0, 0, 0);
        }
#pragma unroll
        for (int r = 0; r < 16; r++) {
            int rw = (r & 3) + 8 * (r >> 2) + 4 * l5;
            if (rw < nv) {
                float nm = snorm[tbase + rw];
                int   dv = sdst[tbase + rw];
                union { ushort u[2]; unsigned int w; } p;
                p.u[0] = f2bf(C0[r] * nm);
                p.u[1] = f2bf(C1[r] * nm);
                ushort* ap = agg + (size_t)dv * D + c0;   // 4B-aligned (c0 even)
                asm volatile("global_atomic_pk_add_bf16 %0, %1, off"
                             :: "v"(ap), "v"(p.w) : "memory");
            }
        }
    }
}

// ---------------- self-loop GEMM (bf16 x + bf16 agg), NO global atomics ----------------
// BN partials: thread -> LDS (128 cols) -> partial[c][block]; reduced by k_colreduce.
__global__ __launch_bounds__(256) void k_loop_nb(
    const ushort* __restrict__ xbf, const ushort* __restrict__ MT,
    const float* __restrict__ bias, const ushort* __restrict__ agg,
    float* __restrict__ out, float* __restrict__ psum, float* __restrict__ psq) {
    __shared__ float lsum[128], lsq[128];
    if (threadIdx.x < 128) { lsum[threadIdx.x] = 0.f; lsq[threadIdx.x] = 0.f; }
    int wid = threadIdx.x >> 6, lane = threadIdx.x & 63;
    int l31 = lane & 31, l5 = lane >> 5;
    int oh  = wid & 1;
    int strm = blockIdx.x * 2 + (wid >> 1);
    const int NSTR = LOOP_GRID2 * 2;   // 1564
    const ushort* MTb = MT + (size_t)NBUCK * (D * D);   // Mloop at index 200
    int ocol0 = oh * 64 + l31, ocol1 = oh * 64 + 32 + l31;
    bf16x8 B0[8], B1[8];
#pragma unroll
    for (int kc = 0; kc < 8; kc++) {
        B0[kc] = *(const bf16x8*)&MTb[(size_t)ocol0 * D + kc * 16 + l5 * 8];
        B1[kc] = *(const bf16x8*)&MTb[(size_t)ocol1 * D + kc * 16 + l5 * 8];
    }
    float b0 = bias[ocol0], b1 = bias[ocol1];
    float ps0 = 0.f, pq0 = 0.f, ps1 = 0.f, pq1 = 0.f;
    const int NT = V_N / 32;   // 3125
    for (int tile = strm; tile < NT; tile += NSTR) {
        int tbase = tile * 32;
        const ushort* xr = xbf + (size_t)(tbase + l31) * D + l5 * 8;
        bf16x8 A[8];
#pragma unroll
        for (int kc = 0; kc < 8; kc++) A[kc] = *(const bf16x8*)(xr + kc * 16);
        f32x16 C0, C1;
#pragma unroll
        for (int i = 0; i < 16; i++) { C0[i] = 0.f; C1[i] = 0.f; }
#pragma unroll
        for (int kc = 0; kc < 8; kc++) {
            C0 = __builtin_amdgcn_mfma_f32_32x32x16_bf16(A[kc], B0[kc], C0, 0, 0, 0);
            C1 = __builtin_amdgcn_mfma_f32_32x32x16_bf16(A[kc], B1[kc], C1, 0, 0, 0);
        }
#pragma unroll
        for (int r = 0; r < 16; r++) {
            int rw = (r & 3) + 8 * (r >> 2) + 4 * l5;
            size_t i0 = (size_t)(tbase + rw) * D + ocol0;
            size_t i1 = (size_t)(tbase + rw) * D + ocol1;
            float h0 = (bf2f((uint32)agg[i0]) + C0[r]) * (1.f / 3.f) + b0;
            float h1 = (bf2f((uint32)agg[i1]) + C1[r]) * (1.f / 3.f) + b1;
            out[i0] = h0; out[i1] = h1;
            ps0 += h0; pq0 += h0 * h0;
            ps1 += h1; pq1 += h1 * h1;
        }
    }
    __syncthreads();   // lsum/lsq init visible
    atomicAdd(&lsum[ocol0], ps0); atomicAdd(&lsq[ocol0], pq0);
    atomicAdd(&lsum[ocol1], ps1); atomicAdd(&lsq[ocol1], pq1);
    __syncthreads();
    if (threadIdx.x < 128) {
        psum[(size_t)threadIdx.x * LOOP_GRID2 + blockIdx.x] = lsum[threadIdx.x];
        psq [(size_t)threadIdx.x * LOOP_GRID2 + blockIdx.x] = lsq [threadIdx.x];
    }
}

// ---------------- reduce BN partials: 1 block per column ----------------
__global__ __launch_bounds__(256) void k_colreduce(
    const float* __restrict__ psum, const float* __restrict__ psq,
    float* __restrict__ colsum, float* __restrict__ colsq) {
    __shared__ float ls[256], lq[256];
    int c = blockIdx.x, tid = threadIdx.x;
    float s = 0.f, q = 0.f;
    for (int b = tid; b < LOOP_GRID2; b += 256) {
        s += psum[(size_t)c * LOOP_GRID2 + b];
        q += psq [(size_t)c * LOOP_GRID2 + b];
    }
    ls[tid] = s; lq[tid] = q;
    __syncthreads();
    for (int off = 128; off > 0; off >>= 1) {
        if (tid < off) { ls[tid] += ls[tid + off]; lq[tid] += lq[tid + off]; }
        __syncthreads();
    }
    if (tid == 0) { colsum[c] = ls[0]; colsq[c] = lq[0]; }
}

// ---------------- legacy (R7) kernels for fallback ----------------
__global__ __launch_bounds__(256) void k_edge_pk(
    const float* __restrict__ x, const ushort* __restrict__ MT,
    const int* __restrict__ starts, const int* __restrict__ ssrc,
    const int* __restrict__ sdst, const float* __restrict__ snorm,
    ushort* __restrict__ agg) {
    int wid  = threadIdx.x >> 6, lane = threadIdx.x & 63;
    int l31  = lane & 31, l5 = lane >> 5;
    int bucket = blockIdx.x / BPB;
    int sib    = (blockIdx.x % BPB) * 2 + (wid >> 1);
    int oh     = wid & 1;
    int bstart = starts[bucket], bend = starts[bucket + 1];
    const ushort* MTb = MT + (size_t)bucket * (D * D);
    int c0 = oh * 64 + 2 * l31;
    bf16x8 B0[8], B1[8];
#pragma unroll
    for (int kc = 0; kc < 8; kc++) {
        B0[kc] = *(const bf16x8*)&MTb[(size_t)c0 * D + kc * 16 + l5 * 8];
        B1[kc] = *(const bf16x8*)&MTb[(size_t)(c0 + 1) * D + kc * 16 + l5 * 8];
    }
    for (int tbase = bstart + sib * 32; tbase < bend; tbase += BPB * 2 * 32) {
        int nv = bend - tbase; if (nv > 32) nv = 32;
        int sr = ssrc[tbase + (l31 < nv ? l31 : 0)];
        const float* xr = x + (size_t)sr * D + l5 * 8;
        bf16x8 A[8];
#pragma unroll
        for (int kc = 0; kc < 8; kc++) {
            f32x4v v0 = *(const f32x4v*)(xr + kc * 16);
            f32x4v v1 = *(const f32x4v*)(xr + kc * 16 + 4);
            union { bf16x8 v; ushort u[8]; } t;
            t.u[0] = f2bf(v0[0]); t.u[1] = f2bf(v0[1]); t.u[2] = f2bf(v0[2]); t.u[3] = f2bf(v0[3]);
            t.u[4] = f2bf(v1[0]); t.u[5] = f2bf(v1[1]); t.u[6] = f2bf(v1[2]); t.u[7] = f2bf(v1[3]);
            A[kc] = t.v;
        }
        f32x16 C0, C1;
#pragma unroll
        for (int i = 0; i < 16; i++) { C0[i] = 0.f; C1[i] = 0.f; }
#pragma unroll
        for (int kc = 0; kc < 8; kc++) {
            C0 = __builtin_amdgcn_mfma_f32_32x32x16_bf16(A[kc], B0[kc], C0, 0, 0, 0);
            C1 = __builtin_amdgcn_mfma_f32_32x32x16_bf16(A[kc], B1[kc], C1, 0, 0, 0);
        }
#pragma unroll
        for (int r = 0; r < 16; r++) {
            int rw = (r & 3) + 8 * (r >> 2) + 4 * l5;
            if (rw < nv) {
                float nm = snorm[tbase + rw];
                int   dv = sdst[tbase + rw];
                union { ushort u[2]; unsigned int w; } p;
                p.u[0] = f2bf(C0[r] * nm);
                p.u[1] = f2bf(C1[r] * nm);
                ushort* ap = agg + (size_t)dv * D + c0;
                asm volatile("global_atomic_pk_add_bf16 %0, %1, off"
                             :: "v"(ap), "v"(p.w) : "memory");
            }
        }
    }
}

constexpr int LOOP_GRID = 400;
__global__ __launch_bounds__(256) void k_loop_pk(
    const float* __restrict__ x, const ushort* __restrict__ MT,
    const float* __restrict__ bias, const ushort* __restrict__ agg,
    float* __restrict__ out, float* __restrict__ colsum, float* __restrict__ colsq) {
    int wid = threadIdx.x >> 6, lane = threadIdx.x & 63;
    int l31 = lane & 31, l5 = lane >> 5;
    int oh  = wid & 1;
    int strm = blockIdx.x * 2 + (wid >> 1);
    const int NSTR = LOOP_GRID * 2;
    const ushort* MTb = MT + (size_t)NBUCK * (D * D);
    int ocol0 = oh * 64 + l31, ocol1 = oh * 64 + 32 + l31;
    bf16x8 B0[8], B1[8];
#pragma unroll
    for (int kc = 0; kc < 8; kc++) {
        B0[kc] = *(const bf16x8*)&MTb[(size_t)ocol0 * D + kc * 16 + l5 * 8];
        B1[kc] = *(const bf16x8*)&MTb[(size_t)ocol1 * D + kc * 16 + l5 * 8];
    }
    float b0 = bias[ocol0], b1 = bias[ocol1];
    float ps0 = 0.f, pq0 = 0.f, ps1 = 0.f, pq1 = 0.f;
    const int NT = V_N / 32;
    for (int tile = strm; tile < NT; tile += NSTR) {
        int tbase = tile * 32;
        const float* xr = x + (size_t)(tbase + l31) * D + l5 * 8;
        bf16x8 A[8];
#pragma unroll
        for (int kc = 0; kc < 8; kc++) {
            f32x4v v0 = *(const f32x4v*)(xr + kc * 16);
            f32x4v v1 = *(const f32x4v*)(xr + kc * 16 + 4);
            union { bf16x8 v; ushort u[8]; } t;
            t.u[0] = f2bf(v0[0]); t.u[1] = f2bf(v0[1]); t.u[2] = f2bf(v0[2]); t.u[3] = f2bf(v0[3]);
            t.u[4] = f2bf(v1[0]); t.u[5] = f2bf(v1[1]); t.u[6] = f2bf(v1[2]); t.u[7] = f2bf(v1[3]);
            A[kc] = t.v;
        }
        f32x16 C0, C1;
#pragma unroll
        for (int i = 0; i < 16; i++) { C0[i] = 0.f; C1[i] = 0.f; }
#pragma unroll
        for (int kc = 0; kc < 8; kc++) {
            C0 = __builtin_amdgcn_mfma_f32_32x32x16_bf16(A[kc], B0[kc], C0, 0, 0, 0);
            C1 = __builtin_amdgcn_mfma_f32_32x32x16_bf16(A[kc], B1[kc], C1, 0, 0, 0);
        }
#pragma unroll
        for (int r = 0; r < 16; r++) {
            int rw = (r & 3) + 8 * (r >> 2) + 4 * l5;
            size_t i0 = (size_t)(tbase + rw) * D + ocol0;
            size_t i1 = (size_t)(tbase + rw) * D + ocol1;
            float h0 = (bf2f((uint32)agg[i0]) + C0[r]) * (1.f / 3.f) + b0;
            float h1 = (bf2f((uint32)agg[i1]) + C1[r]) * (1.f / 3.f) + b1;
            out[i0] = h0; out[i1] = h1;
            ps0 += h0; pq0 += h0 * h0;
            ps1 += h1; pq1 += h1 * h1;
        }
    }
    atomicAdd(&colsum[ocol0], ps0); atomicAdd(&colsq[ocol0], pq0);
    atomicAdd(&colsum[ocol1], ps1); atomicAdd(&colsq[ocol1], pq1);
}

// ---------------- BatchNorm normalize in place ----------------
__global__ void k_bn(float* __restrict__ out, const float* __restrict__ colsum,
                     const float* __restrict__ colsq, const float* __restrict__ gamma,
                     const float* __restrict__ beta) {
    const size_t N4 = (size_t)V_N * D / 4;
    size_t stride = (size_t)gridDim.x * blockDim.x;
    for (size_t q = (size_t)blockIdx.x * blockDim.x + threadIdx.x; q < N4; q += stride) {
        int c4 = (int)(q & 31);
        float4 s  = *(const float4*)&colsum[c4 * 4];
        float4 sq = *(const float4*)&colsq[c4 * 4];
        float4 g  = *(const float4*)&gamma[c4 * 4];
        float4 be = *(const float4*)&beta[c4 * 4];
        float4 h  = *(float4*)&out[q * 4];
        const float inv = 1.f / (float)V_N;
        float m0 = s.x * inv, m1 = s.y * inv, m2 = s.z * inv, m3 = s.w * inv;
        float r0 = rsqrtf(sq.x * inv - m0 * m0 + BN_EPS_F);
        float r1 = rsqrtf(sq.y * inv - m1 * m1 + BN_EPS_F);
        float r2 = rsqrtf(sq.z * inv - m2 * m2 + BN_EPS_F);
        float r3 = rsqrtf(sq.w * inv - m3 * m3 + BN_EPS_F);
        h.x = (h.x - m0) * r0 * g.x + be.x;
        h.y = (h.y - m1) * r1 * g.y + be.y;
        h.z = (h.z - m2) * r2 * g.z + be.z;
        h.w = (h.w - m3) * r3 * g.w + be.w;
        *(float4*)&out[q * 4] = h;
    }
}

extern "C" void kernel_launch(void* const* d_in, const int* in_sizes, int n_in,
                              void* d_out, int out_size, void* d_ws, size_t ws_size,
                              hipStream_t stream) {
    const float* x        = (const float*)d_in[0];
    const float* rel      = (const float*)d_in[1];
    const float* enorm    = (const float*)d_in[2];
    const float* in_w     = (const float*)d_in[3];
    const float* out_w    = (const float*)d_in[4];
    const float* loop_w   = (const float*)d_in[5];
    const float* w_rel    = (const float*)d_in[6];
    const float* loop_rel = (const float*)d_in[7];
    const float* bias     = (const float*)d_in[8];
    const float* gamma    = (const float*)d_in[9];
    const float* beta     = (const float*)d_in[10];
    const int*   esrc     = (const int*)d_in[11];
    const int*   edst     = (const int*)d_in[12];
    const int*   etype    = (const int*)d_in[13];
    float* out = (float*)d_out;
    char*  ws  = (char*)d_ws;

    const int gM = 201, smem = (D * D + 256) * sizeof(float);

    ushort* MT     = (ushort*)(ws + 0);
    int*    ssrc   = (int*)(ws + P_SS_OFF);
    int*    sdst   = (int*)(ws + P_SD_OFF);
    float*  snorm  = (float*)(ws + P_SN_OFF);
    ushort* aggbf  = (ushort*)(ws + P_AGG_OFF);
    int*    hist   = (int*)(ws + P_HIST_OFF);
    int*    coff   = (int*)(ws + P_COFF_OFF);
    float*  colsum = (float*)(ws + P_CS_OFF);
    float*  colsq  = (float*)(ws + P_CQ_OFF);
    int*    counts = (int*)(ws + P_CNT_OFF);
    int*    starts = (int*)(ws + P_ST_OFF);

    // deterministic contention-free counting sort (hist overlays agg region)
    k_hist_chunk<<<NCHUNK, 256, 0, stream>>>(etype, hist);
    k_scan_bucket<<<NBUCK, 64, 0, stream>>>(hist, coff, counts);
    k_scan<<<1, 256, 0, stream>>>(counts, starts);
    k_scatter2<<<NCHUNK, 256, 0, stream>>>(esrc, edst, enorm, etype, starts, coff,
                                           ssrc, sdst, snorm);
    // hist/coff dead; zero the (overlaid) agg buffer, stream-ordered
    hipMemsetAsync(ws + P_AGG_OFF, 0, AGG_BYTES, stream);

    k_build_M<<<gM, 256, smem, stream>>>(rel, in_w, out_w, loop_rel, loop_w, MT);
    k_relw<<<NREL2, D, 0, stream>>>(rel, w_rel, out + (size_t)V_N * D);

    if (ws_size >= WS_NEED2) {
        // ---------- R9 path: bf16 x, atomic-free BN reduction ----------
        ushort* xbf  = (ushort*)(ws + P2_XBF);
        float*  psum = (float*)(ws + P2_PSUM);
        float*  psq  = (float*)(ws + P2_PSQ);

        k_xbf<<<(V_N * D / 8 + 255) / 256, 256, 0, stream>>>(x, xbf);
        k_edge_pkb<<<NBUCK * BPB, 256, 0, stream>>>(xbf, MT, starts, ssrc, sdst, snorm, aggbf);
        k_loop_nb<<<LOOP_GRID2, 256, 0, stream>>>(xbf, MT, bias, aggbf, out, psum, psq);
        k_colreduce<<<128, 256, 0, stream>>>(psum, psq, colsum, colsq);
        k_bn<<<2048, 256, 0, stream>>>(out, colsum, colsq, gamma, beta);
    } else {
        // ---------- R7-measured fallback ----------
        hipMemsetAsync(ws + P_CS_OFF, 0, 1024, stream);
        k_edge_pk<<<NBUCK * BPB, 256, 0, stream>>>(x, MT, starts, ssrc, sdst, snorm, aggbf);
        k_loop_pk<<<LOOP_GRID, 256, 0, stream>>>(x, MT, bias, aggbf, out, colsum, colsq);
        k_bn<<<2048, 256, 0, stream>>>(out, colsum, colsq, gamma, beta);
    }
}